// Round 1
// baseline (581.839 us; speedup 1.0000x reference)
//
#include <hip/hip_runtime.h>

// Problem constants
#define NBATCH 8
// x:    8 x 512 x 512   (logH=9,  logW=9)
// down: 8 x 256 x 256   (logH=8,  logW=8)
// up:   8 x 1024 x 1024 (logH=10, logW=10)

// ---------------------------------------------------------------------------
// conv3x3 (SAME, zero pad, cross-correlation) + bias + residual + clamp(-1,1)
// one thread per output pixel
// ---------------------------------------------------------------------------
__global__ void conv3x3_res_clamp(const float* __restrict__ src,
                                  const float* __restrict__ resid,
                                  const float* __restrict__ wt,   // 9 floats
                                  const float* __restrict__ bias, // 1 float
                                  float* __restrict__ dst,
                                  int logH, int logW)
{
    const int H = 1 << logH;
    const int W = 1 << logW;
    const int total = NBATCH << (logH + logW);
    int idx = blockIdx.x * blockDim.x + threadIdx.x;
    if (idx >= total) return;

    const int w = idx & (W - 1);
    const int h = (idx >> logW) & (H - 1);
    const int b = idx >> (logW + logH);
    const int base = b << (logW + logH);

    // broadcast weight loads (same address all lanes -> L1 broadcast)
    float k00 = wt[0], k01 = wt[1], k02 = wt[2];
    float k10 = wt[3], k11 = wt[4], k12 = wt[5];
    float k20 = wt[6], k21 = wt[7], k22 = wt[8];
    float bs  = bias[0];

    float acc = 0.0f;
    #pragma unroll
    for (int kh = 0; kh < 3; ++kh) {
        int hh = h + kh - 1;
        if (hh < 0 || hh >= H) continue;
        int rowbase = base + (hh << logW);
        #pragma unroll
        for (int kw = 0; kw < 3; ++kw) {
            int ww = w + kw - 1;
            if (ww < 0 || ww >= W) continue;
            float kv = (kh == 0) ? ((kw == 0) ? k00 : (kw == 1) ? k01 : k02)
                     : (kh == 1) ? ((kw == 0) ? k10 : (kw == 1) ? k11 : k12)
                                 : ((kw == 0) ? k20 : (kw == 1) ? k21 : k22);
            acc += src[rowbase + ww] * kv;
        }
    }

    float v = acc + bs + resid[idx];
    v = fminf(1.0f, fmaxf(-1.0f, v));
    dst[idx] = v;
}

// ---------------------------------------------------------------------------
// Fusion kernels: 1x1 conv over [pool/identity/upsample] channels
// ---------------------------------------------------------------------------

// x_out[b,h,w] = c0*avgpool2(up)[h,w] + c1*x[h,w] + c2*down[h>>1,w>>1]   (512x512)
__global__ void fuse_x(const float* __restrict__ X,   // 512^2
                       const float* __restrict__ D,   // 256^2
                       const float* __restrict__ U,   // 1024^2
                       const float* __restrict__ c3,  // 3 floats
                       float* __restrict__ out)
{
    const int total = NBATCH << 18; // 8*512*512
    int idx = blockIdx.x * blockDim.x + threadIdx.x;
    if (idx >= total) return;
    int w = idx & 511;
    int h = (idx >> 9) & 511;
    int b = idx >> 18;

    float c0 = c3[0], c1 = c3[1], c2 = c3[2];

    // avg_pool(up, 2)
    int ub = (b << 20) + ((h << 1) << 10) + (w << 1);
    float p = 0.25f * (U[ub] + U[ub + 1] + U[ub + 1024] + U[ub + 1025]);
    float xv = X[idx];
    float dv = D[(b << 16) + ((h >> 1) << 8) + (w >> 1)];
    out[idx] = c0 * p + c1 * xv + c2 * dv;
}

// down_out[b,h,w] = c0*avgpool4(up) + c1*avgpool2(x) + c2*down[h,w]      (256x256)
__global__ void fuse_down(const float* __restrict__ X,
                          const float* __restrict__ D,
                          const float* __restrict__ U,
                          const float* __restrict__ c3,
                          float* __restrict__ out)
{
    const int total = NBATCH << 16; // 8*256*256
    int idx = blockIdx.x * blockDim.x + threadIdx.x;
    if (idx >= total) return;
    int w = idx & 255;
    int h = (idx >> 8) & 255;
    int b = idx >> 16;

    float c0 = c3[0], c1 = c3[1], c2 = c3[2];

    // avg_pool(up, 4): 4x4 block at (4h, 4w) in 1024x1024
    int ub = (b << 20) + ((h << 2) << 10) + (w << 2);
    float pu = 0.0f;
    #pragma unroll
    for (int r = 0; r < 4; ++r) {
        int rb = ub + (r << 10);
        pu += U[rb] + U[rb + 1] + U[rb + 2] + U[rb + 3];
    }
    pu *= (1.0f / 16.0f);

    // avg_pool(x, 2): 2x2 block at (2h, 2w) in 512x512
    int xb = (b << 18) + ((h << 1) << 9) + (w << 1);
    float px = 0.25f * (X[xb] + X[xb + 1] + X[xb + 512] + X[xb + 513]);

    float dv = D[idx];
    out[idx] = c0 * pu + c1 * px + c2 * dv;
}

// up_out[b,h,w] = c0*up[h,w] + c1*x[h>>1,w>>1] + c2*down[h>>2,w>>2]      (1024x1024)
__global__ void fuse_up(const float* __restrict__ X,
                        const float* __restrict__ D,
                        const float* __restrict__ U,
                        const float* __restrict__ c3,
                        float* __restrict__ out)
{
    const int total = NBATCH << 20; // 8*1024*1024
    int idx = blockIdx.x * blockDim.x + threadIdx.x;
    if (idx >= total) return;
    int w = idx & 1023;
    int h = (idx >> 10) & 1023;
    int b = idx >> 20;

    float c0 = c3[0], c1 = c3[1], c2 = c3[2];

    float uv = U[idx];
    float xv = X[(b << 18) + ((h >> 1) << 9) + (w >> 1)];
    float dv = D[(b << 16) + ((h >> 2) << 8) + (w >> 2)];
    out[idx] = c0 * uv + c1 * xv + c2 * dv;
}

// ---------------------------------------------------------------------------
extern "C" void kernel_launch(void* const* d_in, const int* in_sizes, int n_in,
                              void* d_out, int out_size, void* d_ws, size_t ws_size,
                              hipStream_t stream)
{
    const float* x    = (const float*)d_in[0];
    const float* down = (const float*)d_in[1];
    const float* up   = (const float*)d_in[2];
    const float* BUx  = (const float*)d_in[3];
    const float* BUd  = (const float*)d_in[4];
    const float* BUu  = (const float*)d_in[5];
    const float* wAx  = (const float*)d_in[6];
    const float* bx   = (const float*)d_in[7];
    const float* wAd  = (const float*)d_in[8];
    const float* bd   = (const float*)d_in[9];
    const float* wAu  = (const float*)d_in[10];
    const float* bu   = (const float*)d_in[11];
    const float* c1x  = (const float*)d_in[12];
    const float* c1d  = (const float*)d_in[13];
    const float* c1u  = (const float*)d_in[14];

    float* out = (float*)d_out;
    float* ws  = (float*)d_ws;

    const int NX = NBATCH * 512 * 512;   // 2,097,152
    const int ND = NBATCH * 256 * 256;   //   524,288
    const int NU = NBATCH * 1024 * 1024; // 8,388,608

    float* wsX = ws;             float* outX = out;
    float* wsD = ws + NX;        float* outD = out + NX;
    float* wsU = ws + NX + ND;   float* outU = out + NX + ND;

    const int BLK = 256;
    auto gx = (NX + BLK - 1) / BLK;
    auto gd = (ND + BLK - 1) / BLK;
    auto gu = (NU + BLK - 1) / BLK;

    // 5 iterations per level, ping-pong: in -> ws -> out -> ws -> out -> ws
    // x level (logH=logW=9)
    conv3x3_res_clamp<<<gx, BLK, 0, stream>>>(x,    BUx, wAx, bx, wsX, 9, 9);
    conv3x3_res_clamp<<<gx, BLK, 0, stream>>>(wsX,  BUx, wAx, bx, outX, 9, 9);
    conv3x3_res_clamp<<<gx, BLK, 0, stream>>>(outX, BUx, wAx, bx, wsX, 9, 9);
    conv3x3_res_clamp<<<gx, BLK, 0, stream>>>(wsX,  BUx, wAx, bx, outX, 9, 9);
    conv3x3_res_clamp<<<gx, BLK, 0, stream>>>(outX, BUx, wAx, bx, wsX, 9, 9);

    // down level (logH=logW=8)
    conv3x3_res_clamp<<<gd, BLK, 0, stream>>>(down, BUd, wAd, bd, wsD, 8, 8);
    conv3x3_res_clamp<<<gd, BLK, 0, stream>>>(wsD,  BUd, wAd, bd, outD, 8, 8);
    conv3x3_res_clamp<<<gd, BLK, 0, stream>>>(outD, BUd, wAd, bd, wsD, 8, 8);
    conv3x3_res_clamp<<<gd, BLK, 0, stream>>>(wsD,  BUd, wAd, bd, outD, 8, 8);
    conv3x3_res_clamp<<<gd, BLK, 0, stream>>>(outD, BUd, wAd, bd, wsD, 8, 8);

    // up level (logH=logW=10)
    conv3x3_res_clamp<<<gu, BLK, 0, stream>>>(up,   BUu, wAu, bu, wsU, 10, 10);
    conv3x3_res_clamp<<<gu, BLK, 0, stream>>>(wsU,  BUu, wAu, bu, outU, 10, 10);
    conv3x3_res_clamp<<<gu, BLK, 0, stream>>>(outU, BUu, wAu, bu, wsU, 10, 10);
    conv3x3_res_clamp<<<gu, BLK, 0, stream>>>(wsU,  BUu, wAu, bu, outU, 10, 10);
    conv3x3_res_clamp<<<gu, BLK, 0, stream>>>(outU, BUu, wAu, bu, wsU, 10, 10);

    // fusion: read final levels from ws, write d_out
    fuse_x   <<<gx, BLK, 0, stream>>>(wsX, wsD, wsU, c1x, outX);
    fuse_down<<<gd, BLK, 0, stream>>>(wsX, wsD, wsU, c1d, outD);
    fuse_up  <<<gu, BLK, 0, stream>>>(wsX, wsD, wsU, c1u, outU);
}

// Round 2
// 330.026 us; speedup vs baseline: 1.7630x; 1.7630x over previous
//
#include <hip/hip_runtime.h>

#define NBATCH 8

// ---------------------------------------------------------------------------
// Fused 5-iteration conv3x3+bias+BU+clamp, one 64x64 output tile per block.
// LDS: ping-pong padded buffers 74x74 (stride 76), BU tile 72x72 (stride 76).
// Each iteration computes the fixed 72x72 halo-4 region; the stale outer ring
// corrupts one ring per iteration; the 64x64 interior is exact after 5 iters.
// Out-of-image positions are forced to 0 every iteration (conv zero-padding).
// ---------------------------------------------------------------------------
#define STRD 76
#define NPAD 74          // padded tile dim (64 + 2*5)
#define NREG 72          // computed region dim (64 + 2*4)

__global__ __launch_bounds__(256) void conv5_fused(
    const float* __restrict__ src,
    const float* __restrict__ BU,
    const float* __restrict__ wt,    // 9 floats
    const float* __restrict__ bias,  // 1 float
    float* __restrict__ dst,
    int HW)                          // H == W (512 / 256 / 1024)
{
    __shared__ __align__(16) float bufA[NPAD * STRD];
    __shared__ __align__(16) float bufB[NPAD * STRD];
    __shared__ __align__(16) float buL[NREG * STRD];

    const int tid = threadIdx.x;
    const int bw0 = blockIdx.x * 64;
    const int bh0 = blockIdx.y * 64;
    const long base = (long)blockIdx.z * HW * HW;

    // ---- stage src with halo 5 (zero outside image) ----
    for (int i = tid; i < NPAD * NPAD; i += 256) {
        int r = i / NPAD;
        int c = i - r * NPAD;
        int gh = bh0 + r - 5;
        int gw = bw0 + c - 5;
        bool ok = ((unsigned)gh < (unsigned)HW) && ((unsigned)gw < (unsigned)HW);
        bufA[r * STRD + c] = ok ? src[base + (long)gh * HW + gw] : 0.0f;
    }
    // ---- stage BU with halo 4 (zero outside; out positions masked anyway) ----
    for (int i = tid; i < NREG * NREG; i += 256) {
        int r = i / NREG;
        int c = i - r * NREG;
        int gh = bh0 + r - 4;
        int gw = bw0 + c - 4;
        bool ok = ((unsigned)gh < (unsigned)HW) && ((unsigned)gw < (unsigned)HW);
        buL[r * STRD + c] = ok ? BU[base + (long)gh * HW + gw] : 0.0f;
    }

    const float k00 = wt[0], k01 = wt[1], k02 = wt[2];
    const float k10 = wt[3], k11 = wt[4], k12 = wt[5];
    const float k20 = wt[6], k21 = wt[7], k22 = wt[8];
    const float bs = bias[0];

    float* cur = bufA;
    float* nxt = bufB;

    for (int it = 0; it < 5; ++it) {
        __syncthreads();
        // 72 rows x 18 col-strips of 4 pixels = 1296 strips
        for (int s = tid; s < NREG * 18; s += 256) {
            int row = s / 18;          // 0..71
            int g = s - row * 18;      // 0..17
            int rr = row + 1;          // buffer row 1..72
            int cc = 4 * g;            // read base col (16B aligned)

            const float* r0 = &cur[(rr - 1) * STRD + cc];
            const float* r1 = &cur[rr * STRD + cc];
            const float* r2 = &cur[(rr + 1) * STRD + cc];
            float4 a0 = *(const float4*)r0, b0 = *(const float4*)(r0 + 4);
            float4 a1 = *(const float4*)r1, b1 = *(const float4*)(r1 + 4);
            float4 a2 = *(const float4*)r2, b2 = *(const float4*)(r2 + 4);

            float vx = k00 * a0.x + k01 * a0.y + k02 * a0.z
                     + k10 * a1.x + k11 * a1.y + k12 * a1.z
                     + k20 * a2.x + k21 * a2.y + k22 * a2.z;
            float vy = k00 * a0.y + k01 * a0.z + k02 * a0.w
                     + k10 * a1.y + k11 * a1.z + k12 * a1.w
                     + k20 * a2.y + k21 * a2.z + k22 * a2.w;
            float vz = k00 * a0.z + k01 * a0.w + k02 * b0.x
                     + k10 * a1.z + k11 * a1.w + k12 * b1.x
                     + k20 * a2.z + k21 * a2.w + k22 * b2.x;
            float vw = k00 * a0.w + k01 * b0.x + k02 * b0.y
                     + k10 * a1.w + k11 * b1.x + k12 * b1.y
                     + k20 * a2.w + k21 * b2.x + k22 * b2.y;

            float4 bu = *(const float4*)&buL[row * STRD + cc];
            vx = fminf(1.0f, fmaxf(-1.0f, vx + bs + bu.x));
            vy = fminf(1.0f, fmaxf(-1.0f, vy + bs + bu.y));
            vz = fminf(1.0f, fmaxf(-1.0f, vz + bs + bu.z));
            vw = fminf(1.0f, fmaxf(-1.0f, vw + bs + bu.w));

            // zero-padding mask (only non-trivial on image-edge tiles)
            int gh = bh0 + rr - 5;
            int gw0 = bw0 + cc - 4;    // global col of first output pixel
            bool hok = (unsigned)gh < (unsigned)HW;
            vx = (hok && (unsigned)(gw0 + 0) < (unsigned)HW) ? vx : 0.0f;
            vy = (hok && (unsigned)(gw0 + 1) < (unsigned)HW) ? vy : 0.0f;
            vz = (hok && (unsigned)(gw0 + 2) < (unsigned)HW) ? vz : 0.0f;
            vw = (hok && (unsigned)(gw0 + 3) < (unsigned)HW) ? vw : 0.0f;

            float* wp = &nxt[rr * STRD + cc + 1];
            wp[0] = vx; wp[1] = vy; wp[2] = vz; wp[3] = vw;
        }
        float* t = cur; cur = nxt; nxt = t;
    }
    __syncthreads();

    // ---- store 64x64 interior (buffer coords +5) ----
    for (int i = tid; i < 64 * 64; i += 256) {
        int r = i >> 6;
        int c = i & 63;
        dst[base + (long)(bh0 + r) * HW + (bw0 + c)] = cur[(r + 5) * STRD + (c + 5)];
    }
}

// ---------------------------------------------------------------------------
// Single fused cross-scale 1x1-conv kernel: one thread per down-level pixel.
// Reads U (4x4), X (2x2), D (1) exactly once; writes all three outputs.
// ---------------------------------------------------------------------------
__global__ __launch_bounds__(256) void fuse_all(
    const float* __restrict__ X,   // 8 x 512^2
    const float* __restrict__ D,   // 8 x 256^2
    const float* __restrict__ U,   // 8 x 1024^2
    const float* __restrict__ cx,  // 3 floats (x_out coeffs)
    const float* __restrict__ cd,  // 3 floats (down_out coeffs)
    const float* __restrict__ cu,  // 3 floats (up_out coeffs)
    float* __restrict__ xo, float* __restrict__ dno, float* __restrict__ upo)
{
    const int total = NBATCH << 16;  // 8*256*256
    int idx = blockIdx.x * blockDim.x + threadIdx.x;
    if (idx >= total) return;
    int wd = idx & 255;
    int hd = (idx >> 8) & 255;
    int b  = idx >> 16;

    const float cx0 = cx[0], cx1 = cx[1], cx2 = cx[2];
    const float cd0 = cd[0], cd1 = cd[1], cd2 = cd[2];
    const float cu0 = cu[0], cu1 = cu[1], cu2 = cu[2];

    // load U 4x4 block
    int ub = (b << 20) + ((hd << 2) << 10) + (wd << 2);
    float4 u0 = *(const float4*)&U[ub];
    float4 u1 = *(const float4*)&U[ub + 1024];
    float4 u2 = *(const float4*)&U[ub + 2048];
    float4 u3 = *(const float4*)&U[ub + 3072];
    // load X 2x2 block
    int xb = (b << 18) + ((hd << 1) << 9) + (wd << 1);
    float2 x0 = *(const float2*)&X[xb];
    float2 x1 = *(const float2*)&X[xb + 512];
    // load D
    float dv = D[idx];

    // 2x2 pools of U
    float p00 = 0.25f * (u0.x + u0.y + u1.x + u1.y);
    float p01 = 0.25f * (u0.z + u0.w + u1.z + u1.w);
    float p10 = 0.25f * (u2.x + u2.y + u3.x + u3.y);
    float p11 = 0.25f * (u2.z + u2.w + u3.z + u3.w);
    float pu4 = 0.25f * (p00 + p01 + p10 + p11);           // avgpool4(U)
    float px2 = 0.25f * (x0.x + x0.y + x1.x + x1.y);        // avgpool2(X)

    // down_out
    dno[idx] = cd0 * pu4 + cd1 * px2 + cd2 * dv;

    // x_out 2x2
    float2 xo0, xo1;
    xo0.x = cx0 * p00 + cx1 * x0.x + cx2 * dv;
    xo0.y = cx0 * p01 + cx1 * x0.y + cx2 * dv;
    xo1.x = cx0 * p10 + cx1 * x1.x + cx2 * dv;
    xo1.y = cx0 * p11 + cx1 * x1.y + cx2 * dv;
    *(float2*)&xo[xb]       = xo0;
    *(float2*)&xo[xb + 512] = xo1;

    // up_out 4x4
    float4 o0, o1, o2, o3;
    o0.x = cu0 * u0.x + cu1 * x0.x + cu2 * dv;
    o0.y = cu0 * u0.y + cu1 * x0.x + cu2 * dv;
    o0.z = cu0 * u0.z + cu1 * x0.y + cu2 * dv;
    o0.w = cu0 * u0.w + cu1 * x0.y + cu2 * dv;
    o1.x = cu0 * u1.x + cu1 * x0.x + cu2 * dv;
    o1.y = cu0 * u1.y + cu1 * x0.x + cu2 * dv;
    o1.z = cu0 * u1.z + cu1 * x0.y + cu2 * dv;
    o1.w = cu0 * u1.w + cu1 * x0.y + cu2 * dv;
    o2.x = cu0 * u2.x + cu1 * x1.x + cu2 * dv;
    o2.y = cu0 * u2.y + cu1 * x1.x + cu2 * dv;
    o2.z = cu0 * u2.z + cu1 * x1.y + cu2 * dv;
    o2.w = cu0 * u2.w + cu1 * x1.y + cu2 * dv;
    o3.x = cu0 * u3.x + cu1 * x1.x + cu2 * dv;
    o3.y = cu0 * u3.y + cu1 * x1.x + cu2 * dv;
    o3.z = cu0 * u3.z + cu1 * x1.y + cu2 * dv;
    o3.w = cu0 * u3.w + cu1 * x1.y + cu2 * dv;
    *(float4*)&upo[ub]        = o0;
    *(float4*)&upo[ub + 1024] = o1;
    *(float4*)&upo[ub + 2048] = o2;
    *(float4*)&upo[ub + 3072] = o3;
}

// ---------------------------------------------------------------------------
extern "C" void kernel_launch(void* const* d_in, const int* in_sizes, int n_in,
                              void* d_out, int out_size, void* d_ws, size_t ws_size,
                              hipStream_t stream)
{
    const float* x    = (const float*)d_in[0];
    const float* down = (const float*)d_in[1];
    const float* up   = (const float*)d_in[2];
    const float* BUx  = (const float*)d_in[3];
    const float* BUd  = (const float*)d_in[4];
    const float* BUu  = (const float*)d_in[5];
    const float* wAx  = (const float*)d_in[6];
    const float* bx   = (const float*)d_in[7];
    const float* wAd  = (const float*)d_in[8];
    const float* bd   = (const float*)d_in[9];
    const float* wAu  = (const float*)d_in[10];
    const float* bu   = (const float*)d_in[11];
    const float* c1x  = (const float*)d_in[12];
    const float* c1d  = (const float*)d_in[13];
    const float* c1u  = (const float*)d_in[14];

    float* out = (float*)d_out;
    float* ws  = (float*)d_ws;

    const int NX = NBATCH * 512 * 512;
    const int ND = NBATCH * 256 * 256;
    const int NU = NBATCH * 1024 * 1024;

    float* wsX = ws;
    float* wsD = ws + NX;
    float* wsU = ws + NX + ND;
    float* outX = out;
    float* outD = out + NX;
    float* outU = out + NX + ND;

    // fused 5-iteration conv per level -> final levels into ws
    conv5_fused<<<dim3(512 / 64, 512 / 64, NBATCH), 256, 0, stream>>>(x, BUx, wAx, bx, wsX, 512);
    conv5_fused<<<dim3(256 / 64, 256 / 64, NBATCH), 256, 0, stream>>>(down, BUd, wAd, bd, wsD, 256);
    conv5_fused<<<dim3(1024 / 64, 1024 / 64, NBATCH), 256, 0, stream>>>(up, BUu, wAu, bu, wsU, 1024);

    // single-pass cross-scale fusion
    const int ndown = ND;
    fuse_all<<<(ndown + 255) / 256, 256, 0, stream>>>(wsX, wsD, wsU, c1x, c1d, c1u,
                                                      outX, outD, outU);
}

// Round 3
// 281.698 us; speedup vs baseline: 2.0655x; 1.1716x over previous
//
#include <hip/hip_runtime.h>

#define NBATCH 8
#define STRD 84        // LDS row stride (floats); 84 mod 32 = 20 -> row deltas hit banks 20/8/28
#define LDSROWS 74
#define NSTRIP 342     // 18 row-groups x 19 col-strips per 64x64 tile

// row-dependent column swizzle (+0/+4) breaks the delta-row=8 bank collision
__device__ __forceinline__ int swoff(int br) { return ((br >> 3) & 1) << 2; }

// ---------------------------------------------------------------------------
// All three pyramid levels in ONE dispatch. Per block: one 64x64 output tile.
// LDS ping-pong 74x84 (x2 = 49.7 KB -> 3 blocks/CU). BU+bias and validity
// masks live in registers (static strip ownership). Each thread owns <=2
// strips of 4x4 pixels. Computed region: rows -4..67, cols -6..69 (fixed);
// staged real data rows -5..68, cols -5..68; the stale/garbage margin loses
// one ring per iteration, leaving the exact 64x64 interior after 5 iters.
// Out-of-image positions are re-masked to 0 every iteration (zero padding).
// clamp(-1,1) via fminf/fmaxf sanitizes any garbage (incl. NaN) to finite.
// ---------------------------------------------------------------------------
__global__ __launch_bounds__(256) void conv5_all(
    const float* __restrict__ srcU, const float* __restrict__ buU,
    const float* __restrict__ wtU, const float* __restrict__ bsU,
    const float* __restrict__ srcX, const float* __restrict__ buX,
    const float* __restrict__ wtX, const float* __restrict__ bsX,
    const float* __restrict__ srcD, const float* __restrict__ buD,
    const float* __restrict__ wtD, const float* __restrict__ bsD,
    float* __restrict__ dstU, float* __restrict__ dstX, float* __restrict__ dstD)
{
    __shared__ __align__(16) float bufA[LDSROWS * STRD];
    __shared__ __align__(16) float bufB[LDSROWS * STRD];

    const int tid = threadIdx.x;
    const int blk = blockIdx.x;

    const float* src; const float* BU; const float* wt; const float* bs;
    float* dst; int HW; int tx, ty, b;
    if (blk < 2048) {              // up: 8 x 16 x 16 tiles
        src = srcU; BU = buU; wt = wtU; bs = bsU; dst = dstU; HW = 1024;
        b = blk >> 8; ty = (blk >> 4) & 15; tx = blk & 15;
    } else if (blk < 2560) {       // x: 8 x 8 x 8 tiles
        int t = blk - 2048;
        src = srcX; BU = buX; wt = wtX; bs = bsX; dst = dstX; HW = 512;
        b = t >> 6; ty = (t >> 3) & 7; tx = t & 7;
    } else {                       // down: 8 x 4 x 4 tiles
        int t = blk - 2560;
        src = srcD; BU = buD; wt = wtD; bs = bsD; dst = dstD; HW = 256;
        b = t >> 4; ty = (t >> 2) & 3; tx = t & 3;
    }
    const int bh0 = ty << 6, bw0 = tx << 6;
    const long base = (long)b * HW * HW;

    // ---- stage src (coords -5..68 both dims) into bufA, zero outside image
    for (int i = tid; i < 74 * 74; i += 256) {
        int r = i / 74;            // buffer row 0..73  (row coord r-5)
        int c = i - r * 74;        // staged col index -> buffer col c+1 (col coord c-5)
        int gh = bh0 + r - 5;
        int gw = bw0 + c - 5;
        bool ok = ((unsigned)gh < (unsigned)HW) && ((unsigned)gw < (unsigned)HW);
        bufA[r * STRD + (c + 1) + swoff(r)] = ok ? src[base + (long)gh * HW + gw] : 0.0f;
    }

    const float k00 = wt[0], k01 = wt[1], k02 = wt[2];
    const float k10 = wt[3], k11 = wt[4], k12 = wt[5];
    const float k20 = wt[6], k21 = wt[7], k22 = wt[8];
    const float bias = bs[0];

    // ---- per-thread static strips: s = tid, tid+256 (342 total)
    int   qa[2][6];        // LDS base addr (points at bc0, b128-aligned) per window row
    int   ladj[2];         // left-neighbor offset (0 for leftmost strip: junk-tolerated)
    float4 bu_r[2][4];     // BU + bias per output row
    float4 pm[2][4];       // in-image multiplicative mask per output row
    bool  vld[2];

    #pragma unroll
    for (int k = 0; k < 2; ++k) {
        int s = tid + (k << 8);
        vld[k] = (s < NSTRIP);
        int sr = 0, g = 0;
        if (vld[k]) { sr = s / 19; g = s - sr * 19; }
        ladj[k] = (g == 0) ? 0 : -1;
        #pragma unroll
        for (int rI = 0; rI < 6; ++rI) {
            int br = 4 * sr + rI;
            qa[k][rI] = br * STRD + 4 * g + swoff(br);
        }
        #pragma unroll
        for (int i = 0; i < 4; ++i) {
            int gh = bh0 + 4 * sr - 4 + i;
            bool hok = (unsigned)gh < (unsigned)HW;
            float4 bv, mv;
            float* bvp = (float*)&bv;
            float* mvp = (float*)&mv;
            #pragma unroll
            for (int j = 0; j < 4; ++j) {
                int gw = bw0 + 4 * g - 6 + j;
                bool ok = vld[k] && hok && ((unsigned)gw < (unsigned)HW);
                bvp[j] = ok ? (BU[base + (long)gh * HW + gw] + bias) : 0.0f;
                mvp[j] = ok ? 1.0f : 0.0f;
            }
            bu_r[k][i] = bv;
            pm[k][i] = mv;
        }
    }

    float* cur = bufA;
    float* nxt = bufB;

    for (int it = 0; it < 5; ++it) {
        __syncthreads();
        #pragma unroll
        for (int k = 0; k < 2; ++k) {
            if (!vld[k]) continue;
            // load the 6-row input window
            float  lv[6], rv[6];
            float4 qv[6];
            #pragma unroll
            for (int rI = 0; rI < 6; ++rI) {
                const float* p = cur + qa[k][rI];
                qv[rI] = *(const float4*)p;
                lv[rI] = p[ladj[k]];
                rv[rI] = p[4];
            }
            // compute 4 output rows
            #pragma unroll
            for (int i = 0; i < 4; ++i) {
                float4 bu = bu_r[k][i];
                float4 m  = pm[k][i];
                float4 v;
                v.x = bu.x + k00 * lv[i]     + k01 * qv[i].x   + k02 * qv[i].y
                           + k10 * lv[i + 1] + k11 * qv[i + 1].x + k12 * qv[i + 1].y
                           + k20 * lv[i + 2] + k21 * qv[i + 2].x + k22 * qv[i + 2].y;
                v.y = bu.y + k00 * qv[i].x   + k01 * qv[i].y   + k02 * qv[i].z
                           + k10 * qv[i + 1].x + k11 * qv[i + 1].y + k12 * qv[i + 1].z
                           + k20 * qv[i + 2].x + k21 * qv[i + 2].y + k22 * qv[i + 2].z;
                v.z = bu.z + k00 * qv[i].y   + k01 * qv[i].z   + k02 * qv[i].w
                           + k10 * qv[i + 1].y + k11 * qv[i + 1].z + k12 * qv[i + 1].w
                           + k20 * qv[i + 2].y + k21 * qv[i + 2].z + k22 * qv[i + 2].w;
                v.w = bu.w + k00 * qv[i].z   + k01 * qv[i].w   + k02 * rv[i]
                           + k10 * qv[i + 1].z + k11 * qv[i + 1].w + k12 * rv[i + 1]
                           + k20 * qv[i + 2].z + k21 * qv[i + 2].w + k22 * rv[i + 2];
                v.x = fminf(1.0f, fmaxf(-1.0f, v.x)) * m.x;
                v.y = fminf(1.0f, fmaxf(-1.0f, v.y)) * m.y;
                v.z = fminf(1.0f, fmaxf(-1.0f, v.z)) * m.z;
                v.w = fminf(1.0f, fmaxf(-1.0f, v.w)) * m.w;
                *(float4*)(nxt + qa[k][i + 1]) = v;   // write row br=4sr+1+i, aligned
            }
        }
        float* t = cur; cur = nxt; nxt = t;
    }
    __syncthreads();

    // ---- store 64x64 interior: coord (r,c) -> buffer (r+5, c+6+swoff)
    for (int i = tid; i < 64 * 64; i += 256) {
        int r = i >> 6;
        int c = i & 63;
        int br = r + 5;
        dst[base + (long)(bh0 + r) * HW + (bw0 + c)] =
            cur[br * STRD + (c + 6) + swoff(br)];
    }
}

// ---------------------------------------------------------------------------
// Cross-scale 1x1-conv fusion: one thread per down-level pixel; U/X/D read
// exactly once, all three outputs written.
// ---------------------------------------------------------------------------
__global__ __launch_bounds__(256) void fuse_all(
    const float* __restrict__ X,   // 8 x 512^2
    const float* __restrict__ D,   // 8 x 256^2
    const float* __restrict__ U,   // 8 x 1024^2
    const float* __restrict__ cx,
    const float* __restrict__ cd,
    const float* __restrict__ cu,
    float* __restrict__ xo, float* __restrict__ dno, float* __restrict__ upo)
{
    const int total = NBATCH << 16;  // 8*256*256
    int idx = blockIdx.x * blockDim.x + threadIdx.x;
    if (idx >= total) return;
    int wd = idx & 255;
    int hd = (idx >> 8) & 255;
    int b  = idx >> 16;

    const float cx0 = cx[0], cx1 = cx[1], cx2 = cx[2];
    const float cd0 = cd[0], cd1 = cd[1], cd2 = cd[2];
    const float cu0 = cu[0], cu1 = cu[1], cu2 = cu[2];

    int ub = (b << 20) + ((hd << 2) << 10) + (wd << 2);
    float4 u0 = *(const float4*)&U[ub];
    float4 u1 = *(const float4*)&U[ub + 1024];
    float4 u2 = *(const float4*)&U[ub + 2048];
    float4 u3 = *(const float4*)&U[ub + 3072];
    int xb = (b << 18) + ((hd << 1) << 9) + (wd << 1);
    float2 x0 = *(const float2*)&X[xb];
    float2 x1 = *(const float2*)&X[xb + 512];
    float dv = D[idx];

    float p00 = 0.25f * (u0.x + u0.y + u1.x + u1.y);
    float p01 = 0.25f * (u0.z + u0.w + u1.z + u1.w);
    float p10 = 0.25f * (u2.x + u2.y + u3.x + u3.y);
    float p11 = 0.25f * (u2.z + u2.w + u3.z + u3.w);
    float pu4 = 0.25f * (p00 + p01 + p10 + p11);
    float px2 = 0.25f * (x0.x + x0.y + x1.x + x1.y);

    dno[idx] = cd0 * pu4 + cd1 * px2 + cd2 * dv;

    float2 xo0, xo1;
    xo0.x = cx0 * p00 + cx1 * x0.x + cx2 * dv;
    xo0.y = cx0 * p01 + cx1 * x0.y + cx2 * dv;
    xo1.x = cx0 * p10 + cx1 * x1.x + cx2 * dv;
    xo1.y = cx0 * p11 + cx1 * x1.y + cx2 * dv;
    *(float2*)&xo[xb]       = xo0;
    *(float2*)&xo[xb + 512] = xo1;

    float4 o0, o1, o2, o3;
    o0.x = cu0 * u0.x + cu1 * x0.x + cu2 * dv;
    o0.y = cu0 * u0.y + cu1 * x0.x + cu2 * dv;
    o0.z = cu0 * u0.z + cu1 * x0.y + cu2 * dv;
    o0.w = cu0 * u0.w + cu1 * x0.y + cu2 * dv;
    o1.x = cu0 * u1.x + cu1 * x0.x + cu2 * dv;
    o1.y = cu0 * u1.y + cu1 * x0.x + cu2 * dv;
    o1.z = cu0 * u1.z + cu1 * x0.y + cu2 * dv;
    o1.w = cu0 * u1.w + cu1 * x0.y + cu2 * dv;
    o2.x = cu0 * u2.x + cu1 * x1.x + cu2 * dv;
    o2.y = cu0 * u2.y + cu1 * x1.x + cu2 * dv;
    o2.z = cu0 * u2.z + cu1 * x1.y + cu2 * dv;
    o2.w = cu0 * u2.w + cu1 * x1.y + cu2 * dv;
    o3.x = cu0 * u3.x + cu1 * x1.x + cu2 * dv;
    o3.y = cu0 * u3.y + cu1 * x1.x + cu2 * dv;
    o3.z = cu0 * u3.z + cu1 * x1.y + cu2 * dv;
    o3.w = cu0 * u3.w + cu1 * x1.y + cu2 * dv;
    *(float4*)&upo[ub]        = o0;
    *(float4*)&upo[ub + 1024] = o1;
    *(float4*)&upo[ub + 2048] = o2;
    *(float4*)&upo[ub + 3072] = o3;
}

// ---------------------------------------------------------------------------
extern "C" void kernel_launch(void* const* d_in, const int* in_sizes, int n_in,
                              void* d_out, int out_size, void* d_ws, size_t ws_size,
                              hipStream_t stream)
{
    const float* x    = (const float*)d_in[0];
    const float* down = (const float*)d_in[1];
    const float* up   = (const float*)d_in[2];
    const float* BUx  = (const float*)d_in[3];
    const float* BUd  = (const float*)d_in[4];
    const float* BUu  = (const float*)d_in[5];
    const float* wAx  = (const float*)d_in[6];
    const float* bx   = (const float*)d_in[7];
    const float* wAd  = (const float*)d_in[8];
    const float* bd   = (const float*)d_in[9];
    const float* wAu  = (const float*)d_in[10];
    const float* bu   = (const float*)d_in[11];
    const float* c1x  = (const float*)d_in[12];
    const float* c1d  = (const float*)d_in[13];
    const float* c1u  = (const float*)d_in[14];

    float* out = (float*)d_out;
    float* ws  = (float*)d_ws;

    const int NX = NBATCH * 512 * 512;
    const int ND = NBATCH * 256 * 256;

    float* wsX = ws;
    float* wsD = ws + NX;
    float* wsU = ws + NX + ND;
    float* outX = out;
    float* outD = out + NX;
    float* outU = out + NX + ND;

    // one dispatch, all levels: 2048 up + 512 x + 128 down tiles
    conv5_all<<<2688, 256, 0, stream>>>(
        up,   BUu, wAu, bu,
        x,    BUx, wAx, bx,
        down, BUd, wAd, bd,
        wsU, wsX, wsD);

    fuse_all<<<(ND + 255) / 256, 256, 0, stream>>>(wsX, wsD, wsU, c1x, c1d, c1u,
                                                   outX, outD, outU);
}

// Round 4
// 280.329 us; speedup vs baseline: 2.0756x; 1.0049x over previous
//
#include <hip/hip_runtime.h>

#define NBATCH 8
#define STRD 84        // LDS row: [4 pad][76 cols: -6..69][4 pad] floats; 336B = 21*16B
#define LDSROWS 74     // staged rows -5..68
#define NSTRIP 342     // 18 row-groups x 19 col-quads per 64x64 tile

// ---------------------------------------------------------------------------
// All three pyramid levels in ONE dispatch; one 64x64 output tile per block.
// LDS ping-pong 74x84 (x2 = 49.7 KB -> 3 blocks/CU). Per thread <=2 strips of
// 4x4 pixels. Window reads: 6 rows x 3 aligned float4 (pads supply junk for
// the out-of-region edge columns, which are invalid by the shrink schedule).
// Valid region after iter t: rows/cols [-5+t .. 68-t]; after 5 iters the
// 64x64 interior [0..63] is exact. Out-of-image cells re-masked to 0 each
// iter (zero padding); clamp sanitizes all garbage to finite.
// ---------------------------------------------------------------------------
__global__ __launch_bounds__(256, 3) void conv5_all(
    const float* __restrict__ srcU, const float* __restrict__ buU,
    const float* __restrict__ wtU, const float* __restrict__ bsU,
    const float* __restrict__ srcX, const float* __restrict__ buX,
    const float* __restrict__ wtX, const float* __restrict__ bsX,
    const float* __restrict__ srcD, const float* __restrict__ buD,
    const float* __restrict__ wtD, const float* __restrict__ bsD,
    float* __restrict__ dstU, float* __restrict__ dstX, float* __restrict__ dstD)
{
    __shared__ __align__(16) float bufA[LDSROWS * STRD];
    __shared__ __align__(16) float bufB[LDSROWS * STRD];

    const int tid = threadIdx.x;
    const int blk = blockIdx.x;

    const float* src; const float* BU; const float* wt; const float* bs;
    float* dst; int HW; int tx, ty, b;
    if (blk < 2048) {              // up: 8 x 16 x 16 tiles
        src = srcU; BU = buU; wt = wtU; bs = bsU; dst = dstU; HW = 1024;
        b = blk >> 8; ty = (blk >> 4) & 15; tx = blk & 15;
    } else if (blk < 2560) {       // x: 8 x 8 x 8 tiles
        int t = blk - 2048;
        src = srcX; BU = buX; wt = wtX; bs = bsX; dst = dstX; HW = 512;
        b = t >> 6; ty = (t >> 3) & 7; tx = t & 7;
    } else {                       // down: 8 x 4 x 4 tiles
        int t = blk - 2560;
        src = srcD; BU = buD; wt = wtD; bs = bsD; dst = dstD; HW = 256;
        b = t >> 4; ty = (t >> 2) & 3; tx = t & 3;
    }
    const int bh0 = ty << 6, bw0 = tx << 6;
    const long base = (long)b * HW * HW;

    // ---- stage src rows/cols -5..68 -> buffer (row r, offset c+5), 0 outside
    for (int i = tid; i < 74 * 74; i += 256) {
        int r = i / 74;
        int c = i - r * 74;
        int gh = bh0 + r - 5;
        int gw = bw0 + c - 5;
        bool ok = ((unsigned)gh < (unsigned)HW) && ((unsigned)gw < (unsigned)HW);
        bufA[r * STRD + c + 5] = ok ? src[base + (long)gh * HW + gw] : 0.0f;
    }

    const float k00 = wt[0], k01 = wt[1], k02 = wt[2];
    const float k10 = wt[3], k11 = wt[4], k12 = wt[5];
    const float k20 = wt[6], k21 = wt[7], k22 = wt[8];
    const float bias = bs[0];

    // ---- per-thread static strips: s = tid, tid+256
    // strip (sr,g): outputs rows 4sr-4+i (i=0..3), cols 4g-6+j (j=0..3)
    // window buffer rows 4sr..4sr+5; left quad offset qa0 = 4sr*STRD + 4g
    int    qa0[2];
    float4 bu_r[2][4];     // BU + bias per output row (0 where invalid)
    float  hf[2][4];       // row in-image mask
    float4 wfv[2];         // col in-image mask
    bool   vld[2];

    #pragma unroll
    for (int k = 0; k < 2; ++k) {
        int s = tid + (k << 8);
        vld[k] = (s < NSTRIP);
        int sc = vld[k] ? s : 0;
        int sr = sc / 19, g = sc - sr * 19;
        qa0[k] = (4 * sr) * STRD + 4 * g;

        float* wfp = (float*)&wfv[k];
        #pragma unroll
        for (int j = 0; j < 4; ++j) {
            int gw = bw0 + 4 * g - 6 + j;
            wfp[j] = ((unsigned)gw < (unsigned)HW) ? 1.0f : 0.0f;
        }
        #pragma unroll
        for (int i = 0; i < 4; ++i) {
            int gh = bh0 + 4 * sr - 4 + i;
            bool hok = vld[k] && ((unsigned)gh < (unsigned)HW);
            hf[k][i] = hok ? 1.0f : 0.0f;
            float4 bv;
            float* bvp = (float*)&bv;
            #pragma unroll
            for (int j = 0; j < 4; ++j) {
                int gw = bw0 + 4 * g - 6 + j;
                bool ok = hok && ((unsigned)gw < (unsigned)HW);
                bvp[j] = ok ? (BU[base + (long)gh * HW + gw] + bias) : 0.0f;
            }
            bu_r[k][i] = bv;
        }
    }

    float* cur = bufA;
    float* nxt = bufB;

    for (int it = 0; it < 5; ++it) {
        __syncthreads();
        #pragma unroll
        for (int k = 0; k < 2; ++k) {
            if (!vld[k]) continue;
            const float* bp = cur + qa0[k];
            float4 qL[6], qM[6], qR[6];
            #pragma unroll
            for (int r6 = 0; r6 < 6; ++r6) {
                qL[r6] = *(const float4*)(bp + r6 * STRD);
                qM[r6] = *(const float4*)(bp + r6 * STRD + 4);
                qR[r6] = *(const float4*)(bp + r6 * STRD + 8);
            }
            float* wp = nxt + qa0[k];
            #pragma unroll
            for (int i = 0; i < 4; ++i) {
                float4 bu = bu_r[k][i];
                float4 v;
                v.x = bu.x + k00 * qL[i].w     + k01 * qM[i].x     + k02 * qM[i].y
                           + k10 * qL[i + 1].w + k11 * qM[i + 1].x + k12 * qM[i + 1].y
                           + k20 * qL[i + 2].w + k21 * qM[i + 2].x + k22 * qM[i + 2].y;
                v.y = bu.y + k00 * qM[i].x     + k01 * qM[i].y     + k02 * qM[i].z
                           + k10 * qM[i + 1].x + k11 * qM[i + 1].y + k12 * qM[i + 1].z
                           + k20 * qM[i + 2].x + k21 * qM[i + 2].y + k22 * qM[i + 2].z;
                v.z = bu.z + k00 * qM[i].y     + k01 * qM[i].z     + k02 * qM[i].w
                           + k10 * qM[i + 1].y + k11 * qM[i + 1].z + k12 * qM[i + 1].w
                           + k20 * qM[i + 2].y + k21 * qM[i + 2].z + k22 * qM[i + 2].w;
                v.w = bu.w + k00 * qM[i].z     + k01 * qM[i].w     + k02 * qR[i].x
                           + k10 * qM[i + 1].z + k11 * qM[i + 1].w + k12 * qR[i + 1].x
                           + k20 * qM[i + 2].z + k21 * qM[i + 2].w + k22 * qR[i + 2].x;
                float m = hf[k][i];
                float4 wf = wfv[k];
                v.x = fminf(1.0f, fmaxf(-1.0f, v.x)) * (m * wf.x);
                v.y = fminf(1.0f, fmaxf(-1.0f, v.y)) * (m * wf.y);
                v.z = fminf(1.0f, fmaxf(-1.0f, v.z)) * (m * wf.z);
                v.w = fminf(1.0f, fmaxf(-1.0f, v.w)) * (m * wf.w);
                *(float4*)(wp + (i + 1) * STRD + 4) = v;
            }
        }
        float* t = cur; cur = nxt; nxt = t;
    }
    __syncthreads();

    // ---- store 64x64 interior: (r,c) -> buffer (r+5, c+10)
    for (int i = tid; i < 64 * 64; i += 256) {
        int r = i >> 6;
        int c = i & 63;
        dst[base + (long)(bh0 + r) * HW + (bw0 + c)] = cur[(r + 5) * STRD + c + 10];
    }
}

// ---------------------------------------------------------------------------
// Cross-scale 1x1-conv fusion: one thread per down-level pixel; U/X/D read
// exactly once, all three outputs written.
// ---------------------------------------------------------------------------
__global__ __launch_bounds__(256) void fuse_all(
    const float* __restrict__ X,   // 8 x 512^2
    const float* __restrict__ D,   // 8 x 256^2
    const float* __restrict__ U,   // 8 x 1024^2
    const float* __restrict__ cx,
    const float* __restrict__ cd,
    const float* __restrict__ cu,
    float* __restrict__ xo, float* __restrict__ dno, float* __restrict__ upo)
{
    const int total = NBATCH << 16;  // 8*256*256
    int idx = blockIdx.x * blockDim.x + threadIdx.x;
    if (idx >= total) return;
    int wd = idx & 255;
    int hd = (idx >> 8) & 255;
    int b  = idx >> 16;

    const float cx0 = cx[0], cx1 = cx[1], cx2 = cx[2];
    const float cd0 = cd[0], cd1 = cd[1], cd2 = cd[2];
    const float cu0 = cu[0], cu1 = cu[1], cu2 = cu[2];

    int ub = (b << 20) + ((hd << 2) << 10) + (wd << 2);
    float4 u0 = *(const float4*)&U[ub];
    float4 u1 = *(const float4*)&U[ub + 1024];
    float4 u2 = *(const float4*)&U[ub + 2048];
    float4 u3 = *(const float4*)&U[ub + 3072];
    int xb = (b << 18) + ((hd << 1) << 9) + (wd << 1);
    float2 x0 = *(const float2*)&X[xb];
    float2 x1 = *(const float2*)&X[xb + 512];
    float dv = D[idx];

    float p00 = 0.25f * (u0.x + u0.y + u1.x + u1.y);
    float p01 = 0.25f * (u0.z + u0.w + u1.z + u1.w);
    float p10 = 0.25f * (u2.x + u2.y + u3.x + u3.y);
    float p11 = 0.25f * (u2.z + u2.w + u3.z + u3.w);
    float pu4 = 0.25f * (p00 + p01 + p10 + p11);
    float px2 = 0.25f * (x0.x + x0.y + x1.x + x1.y);

    dno[idx] = cd0 * pu4 + cd1 * px2 + cd2 * dv;

    float2 xo0, xo1;
    xo0.x = cx0 * p00 + cx1 * x0.x + cx2 * dv;
    xo0.y = cx0 * p01 + cx1 * x0.y + cx2 * dv;
    xo1.x = cx0 * p10 + cx1 * x1.x + cx2 * dv;
    xo1.y = cx0 * p11 + cx1 * x1.y + cx2 * dv;
    *(float2*)&xo[xb]       = xo0;
    *(float2*)&xo[xb + 512] = xo1;

    float4 o0, o1, o2, o3;
    o0.x = cu0 * u0.x + cu1 * x0.x + cu2 * dv;
    o0.y = cu0 * u0.y + cu1 * x0.x + cu2 * dv;
    o0.z = cu0 * u0.z + cu1 * x0.y + cu2 * dv;
    o0.w = cu0 * u0.w + cu1 * x0.y + cu2 * dv;
    o1.x = cu0 * u1.x + cu1 * x0.x + cu2 * dv;
    o1.y = cu0 * u1.y + cu1 * x0.x + cu2 * dv;
    o1.z = cu0 * u1.z + cu1 * x0.y + cu2 * dv;
    o1.w = cu0 * u1.w + cu1 * x0.y + cu2 * dv;
    o2.x = cu0 * u2.x + cu1 * x1.x + cu2 * dv;
    o2.y = cu0 * u2.y + cu1 * x1.x + cu2 * dv;
    o2.z = cu0 * u2.z + cu1 * x1.y + cu2 * dv;
    o2.w = cu0 * u2.w + cu1 * x1.y + cu2 * dv;
    o3.x = cu0 * u3.x + cu1 * x1.x + cu2 * dv;
    o3.y = cu0 * u3.y + cu1 * x1.x + cu2 * dv;
    o3.z = cu0 * u3.z + cu1 * x1.y + cu2 * dv;
    o3.w = cu0 * u3.w + cu1 * x1.y + cu2 * dv;
    *(float4*)&upo[ub]        = o0;
    *(float4*)&upo[ub + 1024] = o1;
    *(float4*)&upo[ub + 2048] = o2;
    *(float4*)&upo[ub + 3072] = o3;
}

// ---------------------------------------------------------------------------
extern "C" void kernel_launch(void* const* d_in, const int* in_sizes, int n_in,
                              void* d_out, int out_size, void* d_ws, size_t ws_size,
                              hipStream_t stream)
{
    const float* x    = (const float*)d_in[0];
    const float* down = (const float*)d_in[1];
    const float* up   = (const float*)d_in[2];
    const float* BUx  = (const float*)d_in[3];
    const float* BUd  = (const float*)d_in[4];
    const float* BUu  = (const float*)d_in[5];
    const float* wAx  = (const float*)d_in[6];
    const float* bx   = (const float*)d_in[7];
    const float* wAd  = (const float*)d_in[8];
    const float* bd   = (const float*)d_in[9];
    const float* wAu  = (const float*)d_in[10];
    const float* bu   = (const float*)d_in[11];
    const float* c1x  = (const float*)d_in[12];
    const float* c1d  = (const float*)d_in[13];
    const float* c1u  = (const float*)d_in[14];

    float* out = (float*)d_out;
    float* ws  = (float*)d_ws;

    const int NX = NBATCH * 512 * 512;
    const int ND = NBATCH * 256 * 256;

    float* wsX = ws;
    float* wsD = ws + NX;
    float* wsU = ws + NX + ND;
    float* outX = out;
    float* outD = out + NX;
    float* outU = out + NX + ND;

    // one dispatch, all levels: 2048 up + 512 x + 128 down tiles
    conv5_all<<<2688, 256, 0, stream>>>(
        up,   BUu, wAu, bu,
        x,    BUx, wAx, bx,
        down, BUd, wAd, bd,
        wsU, wsX, wsD);

    fuse_all<<<(ND + 255) / 256, 256, 0, stream>>>(wsX, wsD, wsU, c1x, c1d, c1u,
                                                   outX, outD, outU);
}

// Round 5
// 235.108 us; speedup vs baseline: 2.4748x; 1.1923x over previous
//
#include <hip/hip_runtime.h>

#define NBATCH 8
#define TW 64          // tile width  (output)
#define TH 32          // tile height (output)
#define SROWS 42       // staged rows: image rows -5..36  (TH + 10)
#define SQUADS 20      // staged quads/row: image cols -8..71 (80 floats)
#define STRDQ 80       // LDS row stride in floats
#define NSTRIP 180     // 20 row-pairs x 9 col-octs (region rows -4..35, cols -4..67)
#define NTHR 192

// accumulate one stencil row: window floats [L, m.x..m.w, R], weights ka,kb,kc
__device__ __forceinline__ void acc_row(float4& v, float L, float4 m, float R,
                                        float ka, float kb, float kc) {
    v.x += ka * L   + kb * m.x + kc * m.y;
    v.y += ka * m.x + kb * m.y + kc * m.z;
    v.z += ka * m.y + kb * m.z + kc * m.w;
    v.w += ka * m.z + kb * m.w + kc * R;
}

// ---------------------------------------------------------------------------
// 5 fused conv3x3+bias+BU+clamp iterations; all 3 pyramid levels, one dispatch.
// One 64x32 output tile per 192-thread block. LDS ping-pong 42x80 x2 = 26.9KB.
// Thread t (<180) owns one 8x2-px strip: 16 aligned ds_read_b128 (4 rows x 4
// quads) + 4 aligned ds_write_b128 per iteration. Computed region rows -4..35,
// cols -4..67; validity erodes 1 ring/iter from the staged -5..36/-5..68 rim,
// leaving the exact 64x32 interior after 5 iters. Out-of-image cells are
// re-masked to 0 every iter (true zero-pad semantics at image edges, so no
// erosion there). clamp via fminf/fmaxf sanitizes garbage/NaN to finite.
// ---------------------------------------------------------------------------
__global__ __launch_bounds__(NTHR, 4) void conv5_all(
    const float* __restrict__ srcU, const float* __restrict__ buU,
    const float* __restrict__ wtU, const float* __restrict__ bsU,
    const float* __restrict__ srcX, const float* __restrict__ buX,
    const float* __restrict__ wtX, const float* __restrict__ bsX,
    const float* __restrict__ srcD, const float* __restrict__ buD,
    const float* __restrict__ wtD, const float* __restrict__ bsD,
    float* __restrict__ dstU, float* __restrict__ dstX, float* __restrict__ dstD)
{
    __shared__ __align__(16) float bufA[SROWS * STRDQ];
    __shared__ __align__(16) float bufB[SROWS * STRDQ];

    const int tid = threadIdx.x;
    const int blk = blockIdx.x;

    const float* src; const float* BU; const float* wt; const float* bs;
    float* dst; int HW; int tx, ty, b;
    if (blk < 4096) {                 // up: 8 x (32 ty x 16 tx)
        src = srcU; BU = buU; wt = wtU; bs = bsU; dst = dstU; HW = 1024;
        b = blk >> 9; int rem = blk & 511; ty = rem >> 4; tx = rem & 15;
    } else if (blk < 5120) {          // x: 8 x (16 ty x 8 tx)
        int t = blk - 4096;
        src = srcX; BU = buX; wt = wtX; bs = bsX; dst = dstX; HW = 512;
        b = t >> 7; int rem = t & 127; ty = rem >> 3; tx = rem & 7;
    } else {                          // down: 8 x (8 ty x 4 tx)
        int t = blk - 5120;
        src = srcD; BU = buD; wt = wtD; bs = bsD; dst = dstD; HW = 256;
        b = t >> 5; int rem = t & 31; ty = rem >> 2; tx = rem & 3;
    }
    const int bh0 = ty * TH, bw0 = tx * TW;
    const long base = (long)b * HW * HW;

    // ---- stage: image rows -5..36, cols -8..71 -> bufA (img col c -> buf col c+8)
    for (int q = tid; q < SROWS * SQUADS; q += NTHR) {
        int r = q / SQUADS, cq = q - r * SQUADS;
        int gh = bh0 + r - 5;
        int gw = bw0 + (cq << 2) - 8;
        float4 v = {0.0f, 0.0f, 0.0f, 0.0f};
        if ((unsigned)gh < (unsigned)HW) {
            const float* gp = src + base + (long)gh * HW + gw;
            if (gw >= 0 && gw + 3 < HW) {
                v = *(const float4*)gp;
            } else {
                if ((unsigned)(gw + 0) < (unsigned)HW) v.x = gp[0];
                if ((unsigned)(gw + 1) < (unsigned)HW) v.y = gp[1];
                if ((unsigned)(gw + 2) < (unsigned)HW) v.z = gp[2];
                if ((unsigned)(gw + 3) < (unsigned)HW) v.w = gp[3];
            }
        }
        *(float4*)&bufA[r * STRDQ + (cq << 2)] = v;
    }

    const float k00 = wt[0], k01 = wt[1], k02 = wt[2];
    const float k10 = wt[3], k11 = wt[4], k12 = wt[5];
    const float k20 = wt[6], k21 = wt[7], k22 = wt[8];
    const float bias = bs[0];

    // ---- per-thread strip setup (strip s=tid: rp=s/9 row-pair, j=s%9 col-oct)
    // outputs: image rows 2rp-4+i (i=0,1), cols 8j-4+k (k=0..7)
    // window quads: buffer rows 2rp..2rp+3, quads 8j,8j+4,8j+8,8j+12
    const bool act = (tid < NSTRIP);
    int sc = act ? tid : 0;
    int rp = sc / 9, j = sc - rp * 9;
    const int qbase = (2 * rp) * STRDQ + 8 * j;

    float4 wf0, wf1;                  // column in-image masks (k=0..3, 4..7)
    {
        float* p0 = (float*)&wf0; float* p1 = (float*)&wf1;
        #pragma unroll
        for (int k = 0; k < 4; ++k) {
            p0[k] = ((unsigned)(bw0 + 8 * j - 4 + k) < (unsigned)HW) ? 1.0f : 0.0f;
            p1[k] = ((unsigned)(bw0 + 8 * j + k)     < (unsigned)HW) ? 1.0f : 0.0f;
        }
    }
    float hf[2];
    float4 bu0[2], bu1[2];            // (BU + bias), pre-masked 0 outside image
    #pragma unroll
    for (int i = 0; i < 2; ++i) {
        int gh = bh0 + 2 * rp - 4 + i;
        bool hok = act && ((unsigned)gh < (unsigned)HW);
        hf[i] = hok ? 1.0f : 0.0f;
        float* b0 = (float*)&bu0[i]; float* b1 = (float*)&bu1[i];
        #pragma unroll
        for (int k = 0; k < 4; ++k) {
            int gw0 = bw0 + 8 * j - 4 + k;
            int gw1 = bw0 + 8 * j + k;
            b0[k] = (hok && (unsigned)gw0 < (unsigned)HW)
                        ? (BU[base + (long)gh * HW + gw0] + bias) : 0.0f;
            b1[k] = (hok && (unsigned)gw1 < (unsigned)HW)
                        ? (BU[base + (long)gh * HW + gw1] + bias) : 0.0f;
        }
    }

    float* cur = bufA;
    float* nxt = bufB;

    for (int it = 0; it < 5; ++it) {
        __syncthreads();
        if (act) {
            float4 q[4][4];
            const float* bp = cur + qbase;
            #pragma unroll
            for (int r = 0; r < 4; ++r) {
                q[r][0] = *(const float4*)(bp + r * STRDQ);
                q[r][1] = *(const float4*)(bp + r * STRDQ + 4);
                q[r][2] = *(const float4*)(bp + r * STRDQ + 8);
                q[r][3] = *(const float4*)(bp + r * STRDQ + 12);
            }
            float* wp = nxt + qbase;
            #pragma unroll
            for (int i = 0; i < 2; ++i) {
                float4 v0 = bu0[i];
                float4 v1 = bu1[i];
                acc_row(v0, q[i][0].w,     q[i][1],     q[i][2].x,     k00, k01, k02);
                acc_row(v0, q[i + 1][0].w, q[i + 1][1], q[i + 1][2].x, k10, k11, k12);
                acc_row(v0, q[i + 2][0].w, q[i + 2][1], q[i + 2][2].x, k20, k21, k22);
                acc_row(v1, q[i][1].w,     q[i][2],     q[i][3].x,     k00, k01, k02);
                acc_row(v1, q[i + 1][1].w, q[i + 1][2], q[i + 1][3].x, k10, k11, k12);
                acc_row(v1, q[i + 2][1].w, q[i + 2][2], q[i + 2][3].x, k20, k21, k22);
                float m = hf[i];
                v0.x = fminf(1.0f, fmaxf(-1.0f, v0.x)) * (m * wf0.x);
                v0.y = fminf(1.0f, fmaxf(-1.0f, v0.y)) * (m * wf0.y);
                v0.z = fminf(1.0f, fmaxf(-1.0f, v0.z)) * (m * wf0.z);
                v0.w = fminf(1.0f, fmaxf(-1.0f, v0.w)) * (m * wf0.w);
                v1.x = fminf(1.0f, fmaxf(-1.0f, v1.x)) * (m * wf1.x);
                v1.y = fminf(1.0f, fmaxf(-1.0f, v1.y)) * (m * wf1.y);
                v1.z = fminf(1.0f, fmaxf(-1.0f, v1.z)) * (m * wf1.z);
                v1.w = fminf(1.0f, fmaxf(-1.0f, v1.w)) * (m * wf1.w);
                *(float4*)(wp + (i + 1) * STRDQ + 4) = v0;
                *(float4*)(wp + (i + 1) * STRDQ + 8) = v1;
            }
        }
        float* t = cur; cur = nxt; nxt = t;
    }
    __syncthreads();

    // ---- store 64x32 interior: image (r,c) -> buffer (r+5, c+8), quad-aligned
    for (int i2 = tid; i2 < TH * (TW / 4); i2 += NTHR) {
        int r = i2 >> 4;
        int cq = i2 & 15;
        float4 v = *(const float4*)&cur[(r + 5) * STRDQ + 8 + (cq << 2)];
        *(float4*)&dst[base + (long)(bh0 + r) * HW + bw0 + (cq << 2)] = v;
    }
}

// ---------------------------------------------------------------------------
// Cross-scale 1x1-conv fusion: one thread per down-level pixel; U/X/D read
// exactly once, all three outputs written.
// ---------------------------------------------------------------------------
__global__ __launch_bounds__(256) void fuse_all(
    const float* __restrict__ X,   // 8 x 512^2
    const float* __restrict__ D,   // 8 x 256^2
    const float* __restrict__ U,   // 8 x 1024^2
    const float* __restrict__ cx,
    const float* __restrict__ cd,
    const float* __restrict__ cu,
    float* __restrict__ xo, float* __restrict__ dno, float* __restrict__ upo)
{
    const int total = NBATCH << 16;  // 8*256*256
    int idx = blockIdx.x * blockDim.x + threadIdx.x;
    if (idx >= total) return;
    int wd = idx & 255;
    int hd = (idx >> 8) & 255;
    int b  = idx >> 16;

    const float cx0 = cx[0], cx1 = cx[1], cx2 = cx[2];
    const float cd0 = cd[0], cd1 = cd[1], cd2 = cd[2];
    const float cu0 = cu[0], cu1 = cu[1], cu2 = cu[2];

    int ub = (b << 20) + ((hd << 2) << 10) + (wd << 2);
    float4 u0 = *(const float4*)&U[ub];
    float4 u1 = *(const float4*)&U[ub + 1024];
    float4 u2 = *(const float4*)&U[ub + 2048];
    float4 u3 = *(const float4*)&U[ub + 3072];
    int xb = (b << 18) + ((hd << 1) << 9) + (wd << 1);
    float2 x0 = *(const float2*)&X[xb];
    float2 x1 = *(const float2*)&X[xb + 512];
    float dv = D[idx];

    float p00 = 0.25f * (u0.x + u0.y + u1.x + u1.y);
    float p01 = 0.25f * (u0.z + u0.w + u1.z + u1.w);
    float p10 = 0.25f * (u2.x + u2.y + u3.x + u3.y);
    float p11 = 0.25f * (u2.z + u2.w + u3.z + u3.w);
    float pu4 = 0.25f * (p00 + p01 + p10 + p11);
    float px2 = 0.25f * (x0.x + x0.y + x1.x + x1.y);

    dno[idx] = cd0 * pu4 + cd1 * px2 + cd2 * dv;

    float2 xo0, xo1;
    xo0.x = cx0 * p00 + cx1 * x0.x + cx2 * dv;
    xo0.y = cx0 * p01 + cx1 * x0.y + cx2 * dv;
    xo1.x = cx0 * p10 + cx1 * x1.x + cx2 * dv;
    xo1.y = cx0 * p11 + cx1 * x1.y + cx2 * dv;
    *(float2*)&xo[xb]       = xo0;
    *(float2*)&xo[xb + 512] = xo1;

    float4 o0, o1, o2, o3;
    o0.x = cu0 * u0.x + cu1 * x0.x + cu2 * dv;
    o0.y = cu0 * u0.y + cu1 * x0.x + cu2 * dv;
    o0.z = cu0 * u0.z + cu1 * x0.y + cu2 * dv;
    o0.w = cu0 * u0.w + cu1 * x0.y + cu2 * dv;
    o1.x = cu0 * u1.x + cu1 * x0.x + cu2 * dv;
    o1.y = cu0 * u1.y + cu1 * x0.x + cu2 * dv;
    o1.z = cu0 * u1.z + cu1 * x0.y + cu2 * dv;
    o1.w = cu0 * u1.w + cu1 * x0.y + cu2 * dv;
    o2.x = cu0 * u2.x + cu1 * x1.x + cu2 * dv;
    o2.y = cu0 * u2.y + cu1 * x1.x + cu2 * dv;
    o2.z = cu0 * u2.z + cu1 * x1.y + cu2 * dv;
    o2.w = cu0 * u2.w + cu1 * x1.y + cu2 * dv;
    o3.x = cu0 * u3.x + cu1 * x1.x + cu2 * dv;
    o3.y = cu0 * u3.y + cu1 * x1.x + cu2 * dv;
    o3.z = cu0 * u3.z + cu1 * x1.y + cu2 * dv;
    o3.w = cu0 * u3.w + cu1 * x1.y + cu2 * dv;
    *(float4*)&upo[ub]        = o0;
    *(float4*)&upo[ub + 1024] = o1;
    *(float4*)&upo[ub + 2048] = o2;
    *(float4*)&upo[ub + 3072] = o3;
}

// ---------------------------------------------------------------------------
extern "C" void kernel_launch(void* const* d_in, const int* in_sizes, int n_in,
                              void* d_out, int out_size, void* d_ws, size_t ws_size,
                              hipStream_t stream)
{
    const float* x    = (const float*)d_in[0];
    const float* down = (const float*)d_in[1];
    const float* up   = (const float*)d_in[2];
    const float* BUx  = (const float*)d_in[3];
    const float* BUd  = (const float*)d_in[4];
    const float* BUu  = (const float*)d_in[5];
    const float* wAx  = (const float*)d_in[6];
    const float* bx   = (const float*)d_in[7];
    const float* wAd  = (const float*)d_in[8];
    const float* bd   = (const float*)d_in[9];
    const float* wAu  = (const float*)d_in[10];
    const float* bu   = (const float*)d_in[11];
    const float* c1x  = (const float*)d_in[12];
    const float* c1d  = (const float*)d_in[13];
    const float* c1u  = (const float*)d_in[14];

    float* out = (float*)d_out;
    float* ws  = (float*)d_ws;

    const int NX = NBATCH * 512 * 512;
    const int ND = NBATCH * 256 * 256;

    float* wsX = ws;
    float* wsD = ws + NX;
    float* wsU = ws + NX + ND;
    float* outX = out;
    float* outD = out + NX;
    float* outU = out + NX + ND;

    // one dispatch, all levels: 4096 up + 1024 x + 256 down tiles (64x32 each)
    conv5_all<<<5376, NTHR, 0, stream>>>(
        up,   BUu, wAu, bu,
        x,    BUx, wAx, bx,
        down, BUd, wAd, bd,
        wsU, wsX, wsD);

    fuse_all<<<(ND + 255) / 256, 256, 0, stream>>>(wsX, wsD, wsU, c1x, c1d, c1u,
                                                   outX, outD, outU);
}